// Round 10
// baseline (367.678 us; speedup 1.0000x reference)
//
#include <hip/hip_runtime.h>
#include <hip/hip_bf16.h>

#define A_DIM 1024
#define B_DIM 16
#define DM    512
#define NH    8
#define HD    64

#define LDT 72   // padded LDS leading dim (shorts) for attn/legacy tiles

typedef short s16x8 __attribute__((ext_vector_type(8)));   // 8 bf16, MFMA A/B frag
typedef float f32x4 __attribute__((ext_vector_type(4)));   // MFMA C/D frag

static __device__ __forceinline__ unsigned short f2b(float f) {
    __hip_bfloat16 h = __float2bfloat16(f);
    unsigned short u;
    __builtin_memcpy(&u, &h, 2);
    return u;
}
// packed f32x4 -> bf16x4 (two v_cvt_pk_bf16)
static __device__ __forceinline__ uint2 cvt4(float4 v) {
    __hip_bfloat162 lo = __float22bfloat162_rn(make_float2(v.x, v.y));
    __hip_bfloat162 hi = __float22bfloat162_rn(make_float2(v.z, v.w));
    unsigned int ulo, uhi;
    __builtin_memcpy(&ulo, &lo, 4);
    __builtin_memcpy(&uhi, &hi, 4);
    return make_uint2(ulo, uhi);
}

// async global -> LDS, 16 bytes per lane (LDS dest = wave base + lane*16).
static __device__ __forceinline__ void gl_lds16(const short* g, short* l) {
    __builtin_amdgcn_global_load_lds(
        (const __attribute__((address_space(1))) unsigned int*)g,
        (__attribute__((address_space(3))) unsigned int*)l, 16, 0, 0);
}

// ---------------------------------------------------------------------------
// Prep: one-time f32 -> bf16 of src (blocks 0..4095) and Wq|Wk|Wv|Wo
// (blocks 4096..4607) in a single launch.
// ---------------------------------------------------------------------------
__global__ __launch_bounds__(256) void cvt_all(
    const float* __restrict__ src, short* __restrict__ Sb,
    const float* __restrict__ Wq, const float* __restrict__ Wk,
    const float* __restrict__ Wv, const float* __restrict__ Wo,
    short* __restrict__ Wall)
{
    if (blockIdx.x < 4096) {
        int i = (blockIdx.x * 256 + threadIdx.x) * 8;
        float4 a = *(const float4*)&src[i];
        float4 b = *(const float4*)&src[i + 4];
        *(uint2*)&Sb[i]     = cvt4(a);
        *(uint2*)&Sb[i + 4] = cvt4(b);
    } else {
        int i = (blockIdx.x - 4096) * 256 + threadIdx.x;
        int mat = i >> 15;
        const float* W = (mat == 0) ? Wq : (mat == 1) ? Wk : (mat == 2) ? Wv : Wo;
        int j = (i & 32767) * 8;
        float4 a = *(const float4*)&W[j];
        float4 b = *(const float4*)&W[j + 4];
        *(uint2*)&Wall[mat * (DM * DM) + j]     = cvt4(a);
        *(uint2*)&Wall[mat * (DM * DM) + j + 4] = cvt4(b);
    }
}

// ---------------------------------------------------------------------------
// Kernel 1 (round-6 exact): fused QKV projection, gl_lds staging,
// single-buffered (dbuf regressed: 64KB LDS halves occupancy, round 7).
// ---------------------------------------------------------------------------
__global__ __launch_bounds__(256) void qkv_gemm_bf(
    const short* __restrict__ Sb, const short* __restrict__ Wall,
    const float* __restrict__ bq, const float* __restrict__ bk,
    const float* __restrict__ bv,
    short* __restrict__ Qb, short* __restrict__ Kb, short* __restrict__ Vb)
{
    __shared__ __align__(16) short As[128 * 64];
    __shared__ __align__(16) short Bs[128 * 64];

    const int tid  = threadIdx.x;
    const int wave = tid >> 6, lane = tid & 63;
    const int quad = lane >> 4, l16 = lane & 15;
    const int waveM = (wave >> 1) * 64, waveN = (wave & 1) * 64;
    const int mbase = blockIdx.y * 128;
    const int nbase = blockIdx.x * 128;          // 0..1535
    const int mat   = nbase >> 9;                // 0:Q 1:K 2:V
    const short* Wm   = Wall + mat * (DM * DM);
    const float* bvec = (mat == 0) ? bq : (mat == 1) ? bk : bv;
    short* dst        = (mat == 0) ? Qb : (mat == 1) ? Kb : Vb;
    const float oscale = (mat == 0) ? 0.125f : 1.0f;   // fold HD^-0.5 into Q
    const int wrow0 = nbase & 511;

    const int srow = lane >> 3;
    const int scol = (lane & 7) ^ srow;          // inverse-swizzled source chunk
    const int cxa  = l16 & 7;

    f32x4 acc[4][4];
    #pragma unroll
    for (int i = 0; i < 4; i++)
        #pragma unroll
        for (int j = 0; j < 4; j++)
            acc[i][j] = (f32x4){0.f, 0.f, 0.f, 0.f};

    for (int kb = 0; kb < 8; ++kb) {
        __syncthreads();
        #pragma unroll
        for (int p = 0; p < 4; p++) {
            int ch = wave + p * 4;
            int r  = ch * 8 + srow;
            gl_lds16(&Sb[(mbase + r) * 512 + kb * 64 + scol * 8],
                     &As[ch * 8 * 64]);
            gl_lds16(&Wm[(wrow0 + r) * 512 + kb * 64 + scol * 8],
                     &Bs[ch * 8 * 64]);
        }
        __syncthreads();
        #pragma unroll
        for (int k0i = 0; k0i < 2; k0i++) {
            s16x8 af[4], bf[4];
            #pragma unroll
            for (int mi = 0; mi < 4; mi++)
                af[mi] = *(const s16x8*)&As[(waveM + mi * 16 + l16) * 64
                                            + (((k0i * 4 + quad) ^ cxa) * 8)];
            #pragma unroll
            for (int ni = 0; ni < 4; ni++)
                bf[ni] = *(const s16x8*)&Bs[(waveN + ni * 16 + l16) * 64
                                            + (((k0i * 4 + quad) ^ cxa) * 8)];
            #pragma unroll
            for (int mi = 0; mi < 4; mi++)
                #pragma unroll
                for (int ni = 0; ni < 4; ni++)
                    acc[mi][ni] = __builtin_amdgcn_mfma_f32_16x16x32_bf16(
                        af[mi], bf[ni], acc[mi][ni], 0, 0, 0);
        }
    }

    #pragma unroll
    for (int mi = 0; mi < 4; mi++) {
        #pragma unroll
        for (int ni = 0; ni < 4; ni++) {
            #pragma unroll
            for (int r = 0; r < 4; r++) {
                int t = mbase + waveM + mi * 16 + quad * 4 + r;       // token = a*16+b
                int o = wrow0 + waveN + ni * 16 + l16;                // col in [0,512)
                float v = (acc[mi][ni][r] + bvec[o]) * oscale;
                int a = t >> 4, bb = t & 15, n = o >> 6, d = o & 63;
                dst[((bb * NH + n) * A_DIM + a) * HD + d] = (short)f2b(v);
            }
        }
    }
}

// ---------------------------------------------------------------------------
// Kernel 1 (legacy, f32-staged) — small-workspace fallback.
// ---------------------------------------------------------------------------
__global__ __launch_bounds__(256) void qkv_gemm(
    const float* __restrict__ src,
    const float* __restrict__ Wq, const float* __restrict__ bq,
    const float* __restrict__ Wk, const float* __restrict__ bk,
    const float* __restrict__ Wv, const float* __restrict__ bv,
    short* __restrict__ Qb, short* __restrict__ Kb, short* __restrict__ Vb)
{
    __shared__ short As[128 * LDT];
    __shared__ short Bs[128 * LDT];

    const int tid  = threadIdx.x;
    const int wave = tid >> 6, lane = tid & 63;
    const int quad = lane >> 4, l16 = lane & 15;
    const int waveM = (wave >> 1) * 64, waveN = (wave & 1) * 64;
    const int mbase = blockIdx.y * 128;
    const int nbase = blockIdx.x * 128;
    const int mat   = nbase >> 9;
    const float* W    = (mat == 0) ? Wq : (mat == 1) ? Wk : Wv;
    const float* bvec = (mat == 0) ? bq : (mat == 1) ? bk : bv;
    short* dst        = (mat == 0) ? Qb : (mat == 1) ? Kb : Vb;
    const float oscale = (mat == 0) ? 0.125f : 1.0f;
    const int wrow0 = nbase & 511;

    f32x4 acc[4][4];
    #pragma unroll
    for (int i = 0; i < 4; i++)
        #pragma unroll
        for (int j = 0; j < 4; j++)
            acc[i][j] = (f32x4){0.f, 0.f, 0.f, 0.f};

    for (int kb = 0; kb < 8; ++kb) {
        __syncthreads();
        #pragma unroll
        for (int p = 0; p < 8; p++) {
            int chunk = tid + p * 256;
            int row = chunk >> 4, c = chunk & 15;
            float4 a4 = *(const float4*)&src[(mbase + row) * 512 + kb * 64 + c * 4];
            *(uint2*)&As[row * LDT + c * 4] = cvt4(a4);
            float4 w4 = *(const float4*)&W[(wrow0 + row) * 512 + kb * 64 + c * 4];
            *(uint2*)&Bs[row * LDT + c * 4] = cvt4(w4);
        }
        __syncthreads();
        #pragma unroll
        for (int k0i = 0; k0i < 2; k0i++) {
            s16x8 af[4], bf[4];
            #pragma unroll
            for (int mi = 0; mi < 4; mi++)
                af[mi] = *(const s16x8*)&As[(waveM + mi * 16 + l16) * LDT + (k0i * 4 + quad) * 8];
            #pragma unroll
            for (int ni = 0; ni < 4; ni++)
                bf[ni] = *(const s16x8*)&Bs[(waveN + ni * 16 + l16) * LDT + (k0i * 4 + quad) * 8];
            #pragma unroll
            for (int mi = 0; mi < 4; mi++)
                #pragma unroll
                for (int ni = 0; ni < 4; ni++)
                    acc[mi][ni] = __builtin_amdgcn_mfma_f32_16x16x32_bf16(
                        af[mi], bf[ni], acc[mi][ni], 0, 0, 0);
        }
    }

    #pragma unroll
    for (int mi = 0; mi < 4; mi++) {
        #pragma unroll
        for (int ni = 0; ni < 4; ni++) {
            #pragma unroll
            for (int r = 0; r < 4; r++) {
                int t = mbase + waveM + mi * 16 + quad * 4 + r;
                int o = wrow0 + waveN + ni * 16 + l16;
                float v = (acc[mi][ni][r] + bvec[o]) * oscale;
                int a = t >> 4, bb = t & 15, n = o >> 6, d = o & 63;
                dst[((bb * NH + n) * A_DIM + a) * HD + d] = (short)f2b(v);
            }
        }
    }
}

// ---------------------------------------------------------------------------
// Kernel 2 (v10): dbuf one-barrier attention (round-6 skeleton) with the
// round-0 IN-KERNEL software V transpose (V read directly from Vb [bn][a][d])
// — removes the separate v_tr kernel (~7-8us of pipeline time).
// T1 XCD swizzle kept (round-9: FETCH 146->~120MB).  QK^T/softmax/PV math
// and all per-buffer LDS layouts byte-identical to the verified kernels.
// ---------------------------------------------------------------------------
__global__ __launch_bounds__(256) void attn_kernel2(
    const short* __restrict__ Qb, const short* __restrict__ Kb,
    const short* __restrict__ Vb, const float* __restrict__ bias,
    short* __restrict__ AO)
{
    __shared__ short Ks[2][64 * LDT];
    __shared__ short Vt[2][64 * LDT];    // Vt[d][k], chunk-swizzled (round-0 layout)
    __shared__ short Ps[4][16 * LDT];    // per-wave P tile

    const int tid  = threadIdx.x;
    const int wave = tid >> 6, lane = tid & 63;
    const int quad = lane >> 4, l16 = lane & 15;

    // T1 XCD swizzle (bijective: 2048 wgs -> (bn, qt))
    const int flat = blockIdx.x + 16 * blockIdx.y;
    const int bn   = flat & 127;                     // b*8 + n
    const int qt   = flat >> 7;                      // q-tile 0..15
    const int qrow0 = qt * 64 + wave * 16;           // this wave's first q row

    const short* Qg = Qb + bn * (A_DIM * HD);
    const short* Kg = Kb + bn * (A_DIM * HD);
    const short* Vg = Vb + bn * (A_DIM * HD);        // [a][d]

    s16x8 qf[2];
    #pragma unroll
    for (int k0i = 0; k0i < 2; k0i++)
        qf[k0i] = *(const s16x8*)&Qg[(qrow0 + l16) * HD + k0i * 32 + quad * 8];

    const int srow = tid >> 3, sc = tid & 7;

    float lsum[4];
    f32x4 of[4];
    #pragma unroll
    for (int r = 0; r < 4; r++) lsum[r] = 0.f;
    #pragma unroll
    for (int db = 0; db < 4; db++) of[db] = (f32x4){0.f, 0.f, 0.f, 0.f};

    // prologue: tile 0 -> buf 0 (K vector write; V software transpose)
    s16x8 kpre[2], vpre[2];
    #pragma unroll
    for (int p = 0; p < 2; p++) {
        kpre[p] = *(const s16x8*)&Kg[(srow + p * 32) * HD + sc * 8];
        vpre[p] = *(const s16x8*)&Vg[(srow + p * 32) * HD + sc * 8];
    }
    #pragma unroll
    for (int p = 0; p < 2; p++) {
        int row = srow + p * 32;
        *(s16x8*)&Ks[0][row * LDT + sc * 8] = kpre[p];
        #pragma unroll
        for (int j = 0; j < 8; j++) {
            int d = sc * 8 + j;                // d>>3 == sc
            Vt[0][d * LDT + (((row >> 3) ^ sc) << 3) + (row & 7)] = vpre[p][j];
        }
    }

    int cur = 0;
    for (int kb = 0; kb < 16; ++kb) {
        __syncthreads();   // buf[cur] ready; all reads of buf[cur^1] done

        // issue next tile's global loads (latency hides under compute)
        if (kb < 15) {
            #pragma unroll
            for (int p = 0; p < 2; p++) {
                kpre[p] = *(const s16x8*)&Kg[((kb + 1) * 64 + srow + p * 32) * HD + sc * 8];
                vpre[p] = *(const s16x8*)&Vg[((kb + 1) * 64 + srow + p * 32) * HD + sc * 8];
            }
        }

        // S = Q K^T (+bias folded into exp arg)   C-layout: col=l16, row=quad*4+r
        float sv[4][4];
        #pragma unroll
        for (int cb = 0; cb < 4; cb++) {
            f32x4 s = (f32x4){0.f, 0.f, 0.f, 0.f};
            #pragma unroll
            for (int k0i = 0; k0i < 2; k0i++) {
                s16x8 kf = *(const s16x8*)&Ks[cur][(cb * 16 + l16) * LDT + (k0i * 4 + quad) * 8];
                s = __builtin_amdgcn_mfma_f32_16x16x32_bf16(qf[k0i], kf, s, 0, 0, 0);
            }
            #pragma unroll
            for (int r = 0; r < 4; r++) {
                int arow = qrow0 + quad * 4 + r;
                int kcol = kb * 64 + cb * 16 + l16;
                sv[cb][r] = s[r] + bias[arow * A_DIM + kcol];
            }
        }

        // P = exp(s)  (fixed max: logits are O(6), safe in f32/bf16)
        #pragma unroll
        for (int r = 0; r < 4; r++) {
            int prow = quad * 4 + r;
            #pragma unroll
            for (int cb = 0; cb < 4; cb++) {
                float pv = __expf(sv[cb][r]);
                lsum[r] += pv;
                Ps[wave][prow * LDT + cb * 16 + l16] = (short)f2b(pv);
            }
        }

        // O += P @ V  (wave-local; Vt read uses congruent swizzle)
        #pragma unroll
        for (int k0i = 0; k0i < 2; k0i++) {
            s16x8 pf = *(const s16x8*)&Ps[wave][l16 * LDT + (k0i * 4 + quad) * 8];
            #pragma unroll
            for (int db = 0; db < 4; db++) {
                int rr = db * 16 + l16;
                s16x8 vf = *(const s16x8*)&Vt[cur][rr * LDT +
                            (((k0i * 4 + quad) ^ (rr >> 3)) << 3)];
                of[db] = __builtin_amdgcn_mfma_f32_16x16x32_bf16(pf, vf, of[db], 0, 0, 0);
            }
        }

        // write next tile into the other buffer (readers of buf[cur^1]
        // finished before this iteration's barrier)
        if (kb < 15) {
            #pragma unroll
            for (int p = 0; p < 2; p++) {
                int row = srow + p * 32;
                *(s16x8*)&Ks[cur ^ 1][row * LDT + sc * 8] = kpre[p];
                #pragma unroll
                for (int j = 0; j < 8; j++) {
                    int d = sc * 8 + j;
                    Vt[cur ^ 1][d * LDT + (((row >> 3) ^ sc) << 3) + (row & 7)] = vpre[p][j];
                }
            }
        }
        cur ^= 1;
    }

    #pragma unroll
    for (int r = 0; r < 4; r++) {
        float ps = lsum[r];
        ps += __shfl_xor(ps, 1);
        ps += __shfl_xor(ps, 2);
        ps += __shfl_xor(ps, 4);
        ps += __shfl_xor(ps, 8);
        lsum[r] = 1.0f / ps;
    }

    // epilogue: [A][B][DM] token layout (bf16)
    const int b = bn >> 3, n = bn & 7;
    #pragma unroll
    for (int db = 0; db < 4; db++) {
        #pragma unroll
        for (int r = 0; r < 4; r++) {
            int a = qrow0 + quad * 4 + r;
            int d = db * 16 + l16;
            float v = of[db][r] * lsum[r];
            AO[(a * B_DIM + b) * DM + n * HD + d] = (short)f2b(v);
        }
    }
}

// ---------------------------------------------------------------------------
// Kernel 2 (legacy) — round-0 attention for small workspaces.
// ---------------------------------------------------------------------------
__global__ __launch_bounds__(256) void attn_kernel(
    const short* __restrict__ Qb, const short* __restrict__ Kb,
    const short* __restrict__ Vb, const float* __restrict__ bias,
    short* __restrict__ AO)
{
    __shared__ short Ks[64 * LDT];
    __shared__ short Vt[64 * LDT];
    __shared__ short Ps[4][16 * LDT];

    const int tid  = threadIdx.x;
    const int wave = tid >> 6, lane = tid & 63;
    const int quad = lane >> 4, l16 = lane & 15;
    const int bn = blockIdx.y;
    const int qrow0 = blockIdx.x * 64 + wave * 16;

    const short* Qg = Qb + bn * (A_DIM * HD);
    const short* Kg = Kb + bn * (A_DIM * HD);
    const short* Vg = Vb + bn * (A_DIM * HD);

    s16x8 qf[2];
    #pragma unroll
    for (int k0i = 0; k0i < 2; k0i++)
        qf[k0i] = *(const s16x8*)&Qg[(qrow0 + l16) * HD + k0i * 32 + quad * 8];

    float lsum[4];
    f32x4 of[4];
    #pragma unroll
    for (int r = 0; r < 4; r++) lsum[r] = 0.f;
    #pragma unroll
    for (int db = 0; db < 4; db++) of[db] = (f32x4){0.f, 0.f, 0.f, 0.f};

    for (int kb = 0; kb < 16; ++kb) {
        __syncthreads();
        #pragma unroll
        for (int p = 0; p < 2; p++) {
            int chunk = tid + p * 256;
            int row = chunk >> 3, c = chunk & 7;
            *(s16x8*)&Ks[row * LDT + c * 8] =
                *(const s16x8*)&Kg[(kb * 64 + row) * HD + c * 8];
            s16x8 vv = *(const s16x8*)&Vg[(kb * 64 + row) * HD + c * 8];
            #pragma unroll
            for (int j = 0; j < 8; j++) {
                int d = c * 8 + j;
                Vt[d * LDT + (((row >> 3) ^ c) << 3) + (row & 7)] = vv[j];
            }
        }
        __syncthreads();

        float sv[4][4];
        #pragma unroll
        for (int cb = 0; cb < 4; cb++) {
            f32x4 s = (f32x4){0.f, 0.f, 0.f, 0.f};
            #pragma unroll
            for (int k0i = 0; k0i < 2; k0i++) {
                s16x8 kf = *(const s16x8*)&Ks[(cb * 16 + l16) * LDT + (k0i * 4 + quad) * 8];
                s = __builtin_amdgcn_mfma_f32_16x16x32_bf16(qf[k0i], kf, s, 0, 0, 0);
            }
            #pragma unroll
            for (int r = 0; r < 4; r++) {
                int arow = qrow0 + quad * 4 + r;
                int kcol = kb * 64 + cb * 16 + l16;
                sv[cb][r] = s[r] + bias[arow * A_DIM + kcol];
            }
        }

        #pragma unroll
        for (int r = 0; r < 4; r++) {
            int prow = quad * 4 + r;
            #pragma unroll
            for (int cb = 0; cb < 4; cb++) {
                float pv = __expf(sv[cb][r]);
                lsum[r] += pv;
                Ps[wave][prow * LDT + cb * 16 + l16] = (short)f2b(pv);
            }
        }

        #pragma unroll
        for (int k0i = 0; k0i < 2; k0i++) {
            s16x8 pf = *(const s16x8*)&Ps[wave][l16 * LDT + (k0i * 4 + quad) * 8];
            #pragma unroll
            for (int db = 0; db < 4; db++) {
                int rr = db * 16 + l16;
                s16x8 vf = *(const s16x8*)&Vt[rr * LDT +
                            (((k0i * 4 + quad) ^ (rr >> 3)) << 3)];
                of[db] = __builtin_amdgcn_mfma_f32_16x16x32_bf16(pf, vf, of[db], 0, 0, 0);
            }
        }
    }

    #pragma unroll
    for (int r = 0; r < 4; r++) {
        float ps = lsum[r];
        ps += __shfl_xor(ps, 1);
        ps += __shfl_xor(ps, 2);
        ps += __shfl_xor(ps, 4);
        ps += __shfl_xor(ps, 8);
        lsum[r] = 1.0f / ps;
    }

    const int b = bn >> 3, n = bn & 7;
    #pragma unroll
    for (int db = 0; db < 4; db++) {
        #pragma unroll
        for (int r = 0; r < 4; r++) {
            int a = qrow0 + quad * 4 + r;
            int d = db * 16 + l16;
            float v = of[db][r] * lsum[r];
            AO[(a * B_DIM + b) * DM + n * HD + d] = (short)f2b(v);
        }
    }
}

// ---------------------------------------------------------------------------
// Kernel 3 (round-6 exact): output projection, gl_lds, single-buffered.
// ---------------------------------------------------------------------------
__global__ __launch_bounds__(256) void out_gemm_bf(
    const short* __restrict__ Xin,
    const short* __restrict__ Wob, const float* __restrict__ bo,
    float* __restrict__ out)
{
    __shared__ __align__(16) short As[128 * 64];
    __shared__ __align__(16) short Bs[128 * 64];

    const int tid  = threadIdx.x;
    const int wave = tid >> 6, lane = tid & 63;
    const int quad = lane >> 4, l16 = lane & 15;
    const int waveM = (wave >> 1) * 64, waveN = (wave & 1) * 64;
    const int mbase = blockIdx.y * 128;
    const int nbase = blockIdx.x * 128;   // 0..511

    const int srow = lane >> 3;
    const int scol = (lane & 7) ^ srow;
    const int cxa  = l16 & 7;

    f32x4 acc[4][4];
    #pragma unroll
    for (int i = 0; i < 4; i++)
        #pragma unroll
        for (int j = 0; j < 4; j++)
            acc[i][j] = (f32x4){0.f, 0.f, 0.f, 0.f};

    for (int kb = 0; kb < 8; ++kb) {
        __syncthreads();
        #pragma unroll
        for (int p = 0; p < 4; p++) {
            int ch = wave + p * 4;
            int r  = ch * 8 + srow;
            gl_lds16(&Xin[(mbase + r) * 512 + kb * 64 + scol * 8],
                     &As[ch * 8 * 64]);
            gl_lds16(&Wob[(nbase + r) * 512 + kb * 64 + scol * 8],
                     &Bs[ch * 8 * 64]);
        }
        __syncthreads();
        #pragma unroll
        for (int k0i = 0; k0i < 2; k0i++) {
            s16x8 af[4], bf[4];
            #pragma unroll
            for (int mi = 0; mi < 4; mi++)
                af[mi] = *(const s16x8*)&As[(waveM + mi * 16 + l16) * 64
                                            + (((k0i * 4 + quad) ^ cxa) * 8)];
            #pragma unroll
            for (int ni = 0; ni < 4; ni++)
                bf[ni] = *(const s16x8*)&Bs[(waveN + ni * 16 + l16) * 64
                                            + (((k0i * 4 + quad) ^ cxa) * 8)];
            #pragma unroll
            for (int mi = 0; mi < 4; mi++)
                #pragma unroll
                for (int ni = 0; ni < 4; ni++)
                    acc[mi][ni] = __builtin_amdgcn_mfma_f32_16x16x32_bf16(
                        af[mi], bf[ni], acc[mi][ni], 0, 0, 0);
        }
    }

    #pragma unroll
    for (int mi = 0; mi < 4; mi++) {
        #pragma unroll
        for (int ni = 0; ni < 4; ni++) {
            #pragma unroll
            for (int r = 0; r < 4; r++) {
                int t = mbase + waveM + mi * 16 + quad * 4 + r;
                int o = nbase + waveN + ni * 16 + l16;
                out[t * 512 + o] = acc[mi][ni][r] + bo[o];
            }
        }
    }
}

// ---------------------------------------------------------------------------
// Kernel 3 (legacy, f32-staged Wo) — small-workspace fallback.
// ---------------------------------------------------------------------------
__global__ __launch_bounds__(256) void out_gemm(
    const short* __restrict__ Xin,
    const float* __restrict__ Wo, const float* __restrict__ bo,
    float* __restrict__ out)
{
    __shared__ short As[128 * LDT];
    __shared__ short Bs[128 * LDT];

    const int tid  = threadIdx.x;
    const int wave = tid >> 6, lane = tid & 63;
    const int quad = lane >> 4, l16 = lane & 15;
    const int waveM = (wave >> 1) * 64, waveN = (wave & 1) * 64;
    const int mbase = blockIdx.y * 128;
    const int nbase = blockIdx.x * 128;

    f32x4 acc[4][4];
    #pragma unroll
    for (int i = 0; i < 4; i++)
        #pragma unroll
        for (int j = 0; j < 4; j++)
            acc[i][j] = (f32x4){0.f, 0.f, 0.f, 0.f};

    for (int kb = 0; kb < 8; ++kb) {
        __syncthreads();
        #pragma unroll
        for (int p = 0; p < 4; p++) {
            int chunk = tid + p * 256;
            int row = chunk >> 3, c = chunk & 7;
            *(s16x8*)&As[row * LDT + c * 8] =
                *(const s16x8*)&Xin[(mbase + row) * 512 + kb * 64 + c * 8];
        }
        #pragma unroll
        for (int p = 0; p < 8; p++) {
            int chunk = tid + p * 256;
            int row = chunk >> 4, c = chunk & 15;
            float4 w4 = *(const float4*)&Wo[(nbase + row) * 512 + kb * 64 + c * 4];
            *(uint2*)&Bs[row * LDT + c * 4] = cvt4(w4);
        }
        __syncthreads();
        #pragma unroll
        for (int k0i = 0; k0i < 2; k0i++) {
            s16x8 af[4], bf[4];
            #pragma unroll
            for (int mi = 0; mi < 4; mi++)
                af[mi] = *(const s16x8*)&As[(waveM + mi * 16 + l16) * LDT + (k0i * 4 + quad) * 8];
            #pragma unroll
            for (int ni = 0; ni < 4; ni++)
                bf[ni] = *(const s16x8*)&Bs[(waveN + ni * 16 + l16) * LDT + (k0i * 4 + quad) * 8];
            #pragma unroll
            for (int mi = 0; mi < 4; mi++)
                #pragma unroll
                for (int ni = 0; ni < 4; ni++)
                    acc[mi][ni] = __builtin_amdgcn_mfma_f32_16x16x32_bf16(
                        af[mi], bf[ni], acc[mi][ni], 0, 0, 0);
        }
    }

    #pragma unroll
    for (int mi = 0; mi < 4; mi++) {
        #pragma unroll
        for (int ni = 0; ni < 4; ni++) {
            #pragma unroll
            for (int r = 0; r < 4; r++) {
                int t = mbase + waveM + mi * 16 + quad * 4 + r;
                int o = nbase + waveN + ni * 16 + l16;
                out[t * 512 + o] = acc[mi][ni][r] + bo[o];
            }
        }
    }
}

// ---------------------------------------------------------------------------
extern "C" void kernel_launch(void* const* d_in, const int* in_sizes, int n_in,
                              void* d_out, int out_size, void* d_ws, size_t ws_size,
                              hipStream_t stream) {
    const float* src  = (const float*)d_in[0];
    const float* bias = (const float*)d_in[1];
    const float* Wq   = (const float*)d_in[2];
    const float* bq   = (const float*)d_in[3];
    const float* Wk   = (const float*)d_in[4];
    const float* bk   = (const float*)d_in[5];
    const float* Wv   = (const float*)d_in[6];
    const float* bv   = (const float*)d_in[7];
    const float* Wo   = (const float*)d_in[8];
    const float* bo   = (const float*)d_in[9];

    short* ws = (short*)d_ws;
    short* Qb = ws;                        // [B][NH][A][HD] bf16, 16 MB (Q pre-scaled)
    short* Kb = ws + (size_t)(1 << 23);    // 16 MB
    short* Vb = ws + (size_t)(2 << 23);    // 16 MB

    const bool big2   = ws_size >= (size_t)(66u << 20);   // +Sb/Wall layout
    const bool big_ws = ws_size >= (size_t)(64u << 20);

    if (big2) {
        short* Sb   = ws + (size_t)3 * (1 << 23);   // src bf16, 16 MB (dies after qkv)
        short* Wall = ws + (size_t)4 * (1 << 23);   // Wq|Wk|Wv|Wo bf16, 2 MB
        short* AO   = Sb;                           // attn output overlays dead Sb

        cvt_all<<<dim3(4608), 256, 0, stream>>>(src, Sb, Wq, Wk, Wv, Wo, Wall);
        qkv_gemm_bf<<<dim3(12, 128), 256, 0, stream>>>(Sb, Wall, bq, bk, bv, Qb, Kb, Vb);
        attn_kernel2<<<dim3(16, 128), 256, 0, stream>>>(Qb, Kb, Vb, bias, AO);
        out_gemm_bf<<<dim3(4, 128), 256, 0, stream>>>(AO, Wall + 3 * (DM * DM), bo,
                                                      (float*)d_out);
    } else {
        short* AO = big_ws ? (ws + (size_t)3 * (1 << 23))
                           : (short*)d_out;

        qkv_gemm<<<dim3(12, 128), 256, 0, stream>>>(src, Wq, bq, Wk, bk, Wv, bv, Qb, Kb, Vb);
        attn_kernel<<<dim3(16, 128), 256, 0, stream>>>(Qb, Kb, Vb, bias, AO);

        if (big_ws) {
            out_gemm<<<dim3(4, 128), 256, 0, stream>>>(AO, Wo, bo, (float*)d_out);
        } else {
            float* Cs = (float*)d_ws;
            out_gemm<<<dim3(4, 128), 256, 0, stream>>>(AO, Wo, bo, Cs);
            (void)hipMemcpyAsync(d_out, Cs, (size_t)out_size * sizeof(float),
                                 hipMemcpyDeviceToDevice, stream);
        }
    }
}

// Round 13
// 240.106 us; speedup vs baseline: 1.5313x; 1.5313x over previous
//
#include <hip/hip_runtime.h>
#include <hip/hip_bf16.h>

#define A_DIM 1024
#define B_DIM 16
#define DM    512
#define NH    8
#define HD    64

#define LDT 72   // padded LDS leading dim (shorts) for attn/legacy tiles

typedef short s16x8 __attribute__((ext_vector_type(8)));   // 8 bf16, MFMA A/B frag
typedef float f32x4 __attribute__((ext_vector_type(4)));   // MFMA C/D frag

static __device__ __forceinline__ unsigned short f2b(float f) {
    __hip_bfloat16 h = __float2bfloat16(f);
    unsigned short u;
    __builtin_memcpy(&u, &h, 2);
    return u;
}
// packed f32x4 -> bf16x4 (two v_cvt_pk_bf16)
static __device__ __forceinline__ uint2 cvt4(float4 v) {
    __hip_bfloat162 lo = __float22bfloat162_rn(make_float2(v.x, v.y));
    __hip_bfloat162 hi = __float22bfloat162_rn(make_float2(v.z, v.w));
    unsigned int ulo, uhi;
    __builtin_memcpy(&ulo, &lo, 4);
    __builtin_memcpy(&uhi, &hi, 4);
    return make_uint2(ulo, uhi);
}

// async global -> LDS, 16 bytes per lane (LDS dest = wave base + lane*16).
static __device__ __forceinline__ void gl_lds16(const short* g, short* l) {
    __builtin_amdgcn_global_load_lds(
        (const __attribute__((address_space(1))) unsigned int*)g,
        (__attribute__((address_space(3))) unsigned int*)l, 16, 0, 0);
}

// ---------------------------------------------------------------------------
// Prep: one-time f32 -> bf16 of src (blocks 0..4095) and Wq|Wk|Wv|Wo
// (blocks 4096..4607) in a single launch.
// ---------------------------------------------------------------------------
__global__ __launch_bounds__(256) void cvt_all(
    const float* __restrict__ src, short* __restrict__ Sb,
    const float* __restrict__ Wq, const float* __restrict__ Wk,
    const float* __restrict__ Wv, const float* __restrict__ Wo,
    short* __restrict__ Wall)
{
    if (blockIdx.x < 4096) {
        int i = (blockIdx.x * 256 + threadIdx.x) * 8;
        float4 a = *(const float4*)&src[i];
        float4 b = *(const float4*)&src[i + 4];
        *(uint2*)&Sb[i]     = cvt4(a);
        *(uint2*)&Sb[i + 4] = cvt4(b);
    } else {
        int i = (blockIdx.x - 4096) * 256 + threadIdx.x;
        int mat = i >> 15;
        const float* W = (mat == 0) ? Wq : (mat == 1) ? Wk : (mat == 2) ? Wv : Wo;
        int j = (i & 32767) * 8;
        float4 a = *(const float4*)&W[j];
        float4 b = *(const float4*)&W[j + 4];
        *(uint2*)&Wall[mat * (DM * DM) + j]     = cvt4(a);
        *(uint2*)&Wall[mat * (DM * DM) + j + 4] = cvt4(b);
    }
}

// ---------------------------------------------------------------------------
// V transpose: V[bn][a][d] -> Vt[bn][d][a].  LDS-tiled 64x64, coalesced.
// (Kept as a separate kernel: round-10 proved fusing the transpose into the
// attn dbuf loop destroys the prefetch pipeline — vector staging writes are
// a structural requirement of the one-barrier schedule.)
// ---------------------------------------------------------------------------
__global__ __launch_bounds__(256) void v_tr(
    const short* __restrict__ V, short* __restrict__ Vt)
{
    __shared__ short t[64][74];
    const int bn = blockIdx.y, a0 = blockIdx.x * 64;
    const int rr = threadIdx.x >> 3, c = threadIdx.x & 7;   // rr 0..31, c 0..7

    #pragma unroll
    for (int h = 0; h < 2; h++) {
        int a = rr + h * 32;
        *(s16x8*)&t[a][c * 8] =
            *(const s16x8*)&V[((size_t)bn * A_DIM + a0 + a) * HD + c * 8];
    }
    __syncthreads();
    #pragma unroll
    for (int h = 0; h < 2; h++) {
        int d = rr + h * 32;
        s16x8 y;
        #pragma unroll
        for (int j = 0; j < 8; j++) y[j] = t[c * 8 + j][d];
        *(s16x8*)&Vt[((size_t)bn * HD + d) * A_DIM + a0 + c * 8] = y;
    }
}

// ---------------------------------------------------------------------------
// Kernel 1 (round-6 verified): fused QKV projection, gl_lds staging,
// single-buffered (dbuf regressed: 64KB LDS halves occupancy, round 7).
// ---------------------------------------------------------------------------
__global__ __launch_bounds__(256) void qkv_gemm_bf(
    const short* __restrict__ Sb, const short* __restrict__ Wall,
    const float* __restrict__ bq, const float* __restrict__ bk,
    const float* __restrict__ bv,
    short* __restrict__ Qb, short* __restrict__ Kb, short* __restrict__ Vb)
{
    __shared__ __align__(16) short As[128 * 64];
    __shared__ __align__(16) short Bs[128 * 64];

    const int tid  = threadIdx.x;
    const int wave = tid >> 6, lane = tid & 63;
    const int quad = lane >> 4, l16 = lane & 15;
    const int waveM = (wave >> 1) * 64, waveN = (wave & 1) * 64;
    const int mbase = blockIdx.y * 128;
    const int nbase = blockIdx.x * 128;          // 0..1535
    const int mat   = nbase >> 9;                // 0:Q 1:K 2:V
    const short* Wm   = Wall + mat * (DM * DM);
    const float* bvec = (mat == 0) ? bq : (mat == 1) ? bk : bv;
    short* dst        = (mat == 0) ? Qb : (mat == 1) ? Kb : Vb;
    const float oscale = (mat == 0) ? 0.125f : 1.0f;   // fold HD^-0.5 into Q
    const int wrow0 = nbase & 511;

    const int srow = lane >> 3;
    const int scol = (lane & 7) ^ srow;          // inverse-swizzled source chunk
    const int cxa  = l16 & 7;

    f32x4 acc[4][4];
    #pragma unroll
    for (int i = 0; i < 4; i++)
        #pragma unroll
        for (int j = 0; j < 4; j++)
            acc[i][j] = (f32x4){0.f, 0.f, 0.f, 0.f};

    for (int kb = 0; kb < 8; ++kb) {
        __syncthreads();
        #pragma unroll
        for (int p = 0; p < 4; p++) {
            int ch = wave + p * 4;
            int r  = ch * 8 + srow;
            gl_lds16(&Sb[(mbase + r) * 512 + kb * 64 + scol * 8],
                     &As[ch * 8 * 64]);
            gl_lds16(&Wm[(wrow0 + r) * 512 + kb * 64 + scol * 8],
                     &Bs[ch * 8 * 64]);
        }
        __syncthreads();
        #pragma unroll
        for (int k0i = 0; k0i < 2; k0i++) {
            s16x8 af[4], bf[4];
            #pragma unroll
            for (int mi = 0; mi < 4; mi++)
                af[mi] = *(const s16x8*)&As[(waveM + mi * 16 + l16) * 64
                                            + (((k0i * 4 + quad) ^ cxa) * 8)];
            #pragma unroll
            for (int ni = 0; ni < 4; ni++)
                bf[ni] = *(const s16x8*)&Bs[(waveN + ni * 16 + l16) * 64
                                            + (((k0i * 4 + quad) ^ cxa) * 8)];
            #pragma unroll
            for (int mi = 0; mi < 4; mi++)
                #pragma unroll
                for (int ni = 0; ni < 4; ni++)
                    acc[mi][ni] = __builtin_amdgcn_mfma_f32_16x16x32_bf16(
                        af[mi], bf[ni], acc[mi][ni], 0, 0, 0);
        }
    }

    #pragma unroll
    for (int mi = 0; mi < 4; mi++) {
        #pragma unroll
        for (int ni = 0; ni < 4; ni++) {
            #pragma unroll
            for (int r = 0; r < 4; r++) {
                int t = mbase + waveM + mi * 16 + quad * 4 + r;       // token = a*16+b
                int o = wrow0 + waveN + ni * 16 + l16;                // col in [0,512)
                float v = (acc[mi][ni][r] + bvec[o]) * oscale;
                int a = t >> 4, bb = t & 15, n = o >> 6, d = o & 63;
                dst[((bb * NH + n) * A_DIM + a) * HD + d] = (short)f2b(v);
            }
        }
    }
}

// ---------------------------------------------------------------------------
// Kernel 1 (legacy, f32-staged) — small-workspace fallback.
// ---------------------------------------------------------------------------
__global__ __launch_bounds__(256) void qkv_gemm(
    const float* __restrict__ src,
    const float* __restrict__ Wq, const float* __restrict__ bq,
    const float* __restrict__ Wk, const float* __restrict__ bk,
    const float* __restrict__ Wv, const float* __restrict__ bv,
    short* __restrict__ Qb, short* __restrict__ Kb, short* __restrict__ Vb)
{
    __shared__ short As[128 * LDT];
    __shared__ short Bs[128 * LDT];

    const int tid  = threadIdx.x;
    const int wave = tid >> 6, lane = tid & 63;
    const int quad = lane >> 4, l16 = lane & 15;
    const int waveM = (wave >> 1) * 64, waveN = (wave & 1) * 64;
    const int mbase = blockIdx.y * 128;
    const int nbase = blockIdx.x * 128;
    const int mat   = nbase >> 9;
    const float* W    = (mat == 0) ? Wq : (mat == 1) ? Wk : Wv;
    const float* bvec = (mat == 0) ? bq : (mat == 1) ? bk : bv;
    short* dst        = (mat == 0) ? Qb : (mat == 1) ? Kb : Vb;
    const float oscale = (mat == 0) ? 0.125f : 1.0f;
    const int wrow0 = nbase & 511;

    f32x4 acc[4][4];
    #pragma unroll
    for (int i = 0; i < 4; i++)
        #pragma unroll
        for (int j = 0; j < 4; j++)
            acc[i][j] = (f32x4){0.f, 0.f, 0.f, 0.f};

    for (int kb = 0; kb < 8; ++kb) {
        __syncthreads();
        #pragma unroll
        for (int p = 0; p < 8; p++) {
            int chunk = tid + p * 256;
            int row = chunk >> 4, c = chunk & 15;
            float4 a4 = *(const float4*)&src[(mbase + row) * 512 + kb * 64 + c * 4];
            *(uint2*)&As[row * LDT + c * 4] = cvt4(a4);
            float4 w4 = *(const float4*)&W[(wrow0 + row) * 512 + kb * 64 + c * 4];
            *(uint2*)&Bs[row * LDT + c * 4] = cvt4(w4);
        }
        __syncthreads();
        #pragma unroll
        for (int k0i = 0; k0i < 2; k0i++) {
            s16x8 af[4], bf[4];
            #pragma unroll
            for (int mi = 0; mi < 4; mi++)
                af[mi] = *(const s16x8*)&As[(waveM + mi * 16 + l16) * LDT + (k0i * 4 + quad) * 8];
            #pragma unroll
            for (int ni = 0; ni < 4; ni++)
                bf[ni] = *(const s16x8*)&Bs[(waveN + ni * 16 + l16) * LDT + (k0i * 4 + quad) * 8];
            #pragma unroll
            for (int mi = 0; mi < 4; mi++)
                #pragma unroll
                for (int ni = 0; ni < 4; ni++)
                    acc[mi][ni] = __builtin_amdgcn_mfma_f32_16x16x32_bf16(
                        af[mi], bf[ni], acc[mi][ni], 0, 0, 0);
        }
    }

    #pragma unroll
    for (int mi = 0; mi < 4; mi++) {
        #pragma unroll
        for (int ni = 0; ni < 4; ni++) {
            #pragma unroll
            for (int r = 0; r < 4; r++) {
                int t = mbase + waveM + mi * 16 + quad * 4 + r;
                int o = wrow0 + waveN + ni * 16 + l16;
                float v = (acc[mi][ni][r] + bvec[o]) * oscale;
                int a = t >> 4, bb = t & 15, n = o >> 6, d = o & 63;
                dst[((bb * NH + n) * A_DIM + a) * HD + d] = (short)f2b(v);
            }
        }
    }
}

// ---------------------------------------------------------------------------
// Kernel 2 (round-9 verified): dbuf one-barrier attention, V pre-transposed
// in global ([bn][d][a]) so staging is vector-only, T1 XCD swizzle
// (flat = bx + 16*by; bn = flat & 127 keeps all 16 q-tiles of a bn on one
// XCD -> K/V L2-resident; FETCH 146 -> ~120 MB).
// ---------------------------------------------------------------------------
__global__ __launch_bounds__(256) void attn_kernel2(
    const short* __restrict__ Qb, const short* __restrict__ Kb,
    const short* __restrict__ Vtg, const float* __restrict__ bias,
    short* __restrict__ AO)
{
    __shared__ short Ks[2][64 * LDT];
    __shared__ short Vt[2][64 * LDT];    // Vt[d][k], chunk-swizzled (round-0 layout)
    __shared__ short Ps[4][16 * LDT];    // per-wave P tile

    const int tid  = threadIdx.x;
    const int wave = tid >> 6, lane = tid & 63;
    const int quad = lane >> 4, l16 = lane & 15;

    // T1 XCD swizzle (bijective: 2048 wgs -> (bn, qt))
    const int flat = blockIdx.x + 16 * blockIdx.y;
    const int bn   = flat & 127;                     // b*8 + n
    const int qt   = flat >> 7;                      // q-tile 0..15
    const int qrow0 = qt * 64 + wave * 16;           // this wave's first q row

    const short* Qg = Qb  + bn * (A_DIM * HD);
    const short* Kg = Kb  + bn * (A_DIM * HD);
    const short* Vg = Vtg + bn * (HD * A_DIM);       // [d][a]

    s16x8 qf[2];
    #pragma unroll
    for (int k0i = 0; k0i < 2; k0i++)
        qf[k0i] = *(const s16x8*)&Qg[(qrow0 + l16) * HD + k0i * 32 + quad * 8];

    const int srow = tid >> 3, sc = tid & 7;

    float lsum[4];
    f32x4 of[4];
    #pragma unroll
    for (int r = 0; r < 4; r++) lsum[r] = 0.f;
    #pragma unroll
    for (int db = 0; db < 4; db++) of[db] = (f32x4){0.f, 0.f, 0.f, 0.f};

    // prologue: tile 0 -> buf 0
    s16x8 kpre[2], vpre[2];
    #pragma unroll
    for (int p = 0; p < 2; p++) {
        kpre[p] = *(const s16x8*)&Kg[(srow + p * 32) * HD + sc * 8];
        vpre[p] = *(const s16x8*)&Vg[(srow + p * 32) * A_DIM + sc * 8];
    }
    #pragma unroll
    for (int p = 0; p < 2; p++) {
        int row = srow + p * 32;
        *(s16x8*)&Ks[0][row * LDT + sc * 8] = kpre[p];
        *(s16x8*)&Vt[0][row * LDT + ((sc ^ (wave + p * 4)) << 3)] = vpre[p];
    }

    int cur = 0;
    for (int kb = 0; kb < 16; ++kb) {
        __syncthreads();   // buf[cur] ready; all reads of buf[cur^1] done

        if (kb < 15) {
            #pragma unroll
            for (int p = 0; p < 2; p++) {
                kpre[p] = *(const s16x8*)&Kg[((kb + 1) * 64 + srow + p * 32) * HD + sc * 8];
                vpre[p] = *(const s16x8*)&Vg[(srow + p * 32) * A_DIM + (kb + 1) * 64 + sc * 8];
            }
        }

        // S = Q K^T (+bias folded into exp arg)   C-layout: col=l16, row=quad*4+r
        float sv[4][4];
        #pragma unroll
        for (int cb = 0; cb < 4; cb++) {
            f32x4 s = (f32x4){0.f, 0.f, 0.f, 0.f};
            #pragma unroll
            for (int k0i = 0; k0i < 2; k0i++) {
                s16x8 kf = *(const s16x8*)&Ks[cur][(cb * 16 + l16) * LDT + (k0i * 4 + quad) * 8];
                s = __builtin_amdgcn_mfma_f32_16x16x32_bf16(qf[k0i], kf, s, 0, 0, 0);
            }
            #pragma unroll
            for (int r = 0; r < 4; r++) {
                int arow = qrow0 + quad * 4 + r;
                int kcol = kb * 64 + cb * 16 + l16;
                sv[cb][r] = s[r] + bias[arow * A_DIM + kcol];
            }
        }

        // P = exp(s)  (fixed max: logits are O(6), safe in f32/bf16)
        #pragma unroll
        for (int r = 0; r < 4; r++) {
            int prow = quad * 4 + r;
            #pragma unroll
            for (int cb = 0; cb < 4; cb++) {
                float pv = __expf(sv[cb][r]);
                lsum[r] += pv;
                Ps[wave][prow * LDT + cb * 16 + l16] = (short)f2b(pv);
            }
        }

        // O += P @ V  (wave-local; Vt read uses congruent swizzle)
        #pragma unroll
        for (int k0i = 0; k0i < 2; k0i++) {
            s16x8 pf = *(const s16x8*)&Ps[wave][l16 * LDT + (k0i * 4 + quad) * 8];
            #pragma unroll
            for (int db = 0; db < 4; db++) {
                int rr = db * 16 + l16;
                s16x8 vf = *(const s16x8*)&Vt[cur][rr * LDT +
                            (((k0i * 4 + quad) ^ (rr >> 3)) << 3)];
                of[db] = __builtin_amdgcn_mfma_f32_16x16x32_bf16(pf, vf, of[db], 0, 0, 0);
            }
        }

        if (kb < 15) {
            #pragma unroll
            for (int p = 0; p < 2; p++) {
                int row = srow + p * 32;
                *(s16x8*)&Ks[cur ^ 1][row * LDT + sc * 8] = kpre[p];
                *(s16x8*)&Vt[cur ^ 1][row * LDT + ((sc ^ (wave + p * 4)) << 3)] = vpre[p];
            }
        }
        cur ^= 1;
    }

    #pragma unroll
    for (int r = 0; r < 4; r++) {
        float ps = lsum[r];
        ps += __shfl_xor(ps, 1);
        ps += __shfl_xor(ps, 2);
        ps += __shfl_xor(ps, 4);
        ps += __shfl_xor(ps, 8);
        lsum[r] = 1.0f / ps;
    }

    // epilogue: [A][B][DM] token layout (bf16)
    const int b = bn >> 3, n = bn & 7;
    #pragma unroll
    for (int db = 0; db < 4; db++) {
        #pragma unroll
        for (int r = 0; r < 4; r++) {
            int a = qrow0 + quad * 4 + r;
            int d = db * 16 + l16;
            float v = of[db][r] * lsum[r];
            AO[(a * B_DIM + b) * DM + n * HD + d] = (short)f2b(v);
        }
    }
}

// ---------------------------------------------------------------------------
// Kernel 2 (legacy) — round-0 attention for small workspaces.
// ---------------------------------------------------------------------------
__global__ __launch_bounds__(256) void attn_kernel(
    const short* __restrict__ Qb, const short* __restrict__ Kb,
    const short* __restrict__ Vb, const float* __restrict__ bias,
    short* __restrict__ AO)
{
    __shared__ short Ks[64 * LDT];
    __shared__ short Vt[64 * LDT];
    __shared__ short Ps[4][16 * LDT];

    const int tid  = threadIdx.x;
    const int wave = tid >> 6, lane = tid & 63;
    const int quad = lane >> 4, l16 = lane & 15;
    const int bn = blockIdx.y;
    const int qrow0 = blockIdx.x * 64 + wave * 16;

    const short* Qg = Qb + bn * (A_DIM * HD);
    const short* Kg = Kb + bn * (A_DIM * HD);
    const short* Vg = Vb + bn * (A_DIM * HD);

    s16x8 qf[2];
    #pragma unroll
    for (int k0i = 0; k0i < 2; k0i++)
        qf[k0i] = *(const s16x8*)&Qg[(qrow0 + l16) * HD + k0i * 32 + quad * 8];

    float lsum[4];
    f32x4 of[4];
    #pragma unroll
    for (int r = 0; r < 4; r++) lsum[r] = 0.f;
    #pragma unroll
    for (int db = 0; db < 4; db++) of[db] = (f32x4){0.f, 0.f, 0.f, 0.f};

    for (int kb = 0; kb < 16; ++kb) {
        __syncthreads();
        #pragma unroll
        for (int p = 0; p < 2; p++) {
            int chunk = tid + p * 256;
            int row = chunk >> 3, c = chunk & 7;
            *(s16x8*)&Ks[row * LDT + c * 8] =
                *(const s16x8*)&Kg[(kb * 64 + row) * HD + c * 8];
            s16x8 vv = *(const s16x8*)&Vg[(kb * 64 + row) * HD + c * 8];
            #pragma unroll
            for (int j = 0; j < 8; j++) {
                int d = c * 8 + j;
                Vt[d * LDT + (((row >> 3) ^ c) << 3) + (row & 7)] = vv[j];
            }
        }
        __syncthreads();

        float sv[4][4];
        #pragma unroll
        for (int cb = 0; cb < 4; cb++) {
            f32x4 s = (f32x4){0.f, 0.f, 0.f, 0.f};
            #pragma unroll
            for (int k0i = 0; k0i < 2; k0i++) {
                s16x8 kf = *(const s16x8*)&Ks[(cb * 16 + l16) * LDT + (k0i * 4 + quad) * 8];
                s = __builtin_amdgcn_mfma_f32_16x16x32_bf16(qf[k0i], kf, s, 0, 0, 0);
            }
            #pragma unroll
            for (int r = 0; r < 4; r++) {
                int arow = qrow0 + quad * 4 + r;
                int kcol = kb * 64 + cb * 16 + l16;
                sv[cb][r] = s[r] + bias[arow * A_DIM + kcol];
            }
        }

        #pragma unroll
        for (int r = 0; r < 4; r++) {
            int prow = quad * 4 + r;
            #pragma unroll
            for (int cb = 0; cb < 4; cb++) {
                float pv = __expf(sv[cb][r]);
                lsum[r] += pv;
                Ps[wave][prow * LDT + cb * 16 + l16] = (short)f2b(pv);
            }
        }

        #pragma unroll
        for (int k0i = 0; k0i < 2; k0i++) {
            s16x8 pf = *(const s16x8*)&Ps[wave][l16 * LDT + (k0i * 4 + quad) * 8];
            #pragma unroll
            for (int db = 0; db < 4; db++) {
                int rr = db * 16 + l16;
                s16x8 vf = *(const s16x8*)&Vt[rr * LDT +
                            (((k0i * 4 + quad) ^ (rr >> 3)) << 3)];
                of[db] = __builtin_amdgcn_mfma_f32_16x16x32_bf16(pf, vf, of[db], 0, 0, 0);
            }
        }
    }

    #pragma unroll
    for (int r = 0; r < 4; r++) {
        float ps = lsum[r];
        ps += __shfl_xor(ps, 1);
        ps += __shfl_xor(ps, 2);
        ps += __shfl_xor(ps, 4);
        ps += __shfl_xor(ps, 8);
        lsum[r] = 1.0f / ps;
    }

    const int b = bn >> 3, n = bn & 7;
    #pragma unroll
    for (int db = 0; db < 4; db++) {
        #pragma unroll
        for (int r = 0; r < 4; r++) {
            int a = qrow0 + quad * 4 + r;
            int d = db * 16 + l16;
            float v = of[db][r] * lsum[r];
            AO[(a * B_DIM + b) * DM + n * HD + d] = (short)f2b(v);
        }
    }
}

// ---------------------------------------------------------------------------
// Kernel 3 (round-6 verified): output projection, gl_lds, single-buffered.
// ---------------------------------------------------------------------------
__global__ __launch_bounds__(256) void out_gemm_bf(
    const short* __restrict__ Xin,
    const short* __restrict__ Wob, const float* __restrict__ bo,
    float* __restrict__ out)
{
    __shared__ __align__(16) short As[128 * 64];
    __shared__ __align__(16) short Bs[128 * 64];

    const int tid  = threadIdx.x;
    const int wave = tid >> 6, lane = tid & 63;
    const int quad = lane >> 4, l16 = lane & 15;
    const int waveM = (wave >> 1) * 64, waveN = (wave & 1) * 64;
    const int mbase = blockIdx.y * 128;
    const int nbase = blockIdx.x * 128;   // 0..511

    const int srow = lane >> 3;
    const int scol = (lane & 7) ^ srow;
    const int cxa  = l16 & 7;

    f32x4 acc[4][4];
    #pragma unroll
    for (int i = 0; i < 4; i++)
        #pragma unroll
        for (int j = 0; j < 4; j++)
            acc[i][j] = (f32x4){0.f, 0.f, 0.f, 0.f};

    for (int kb = 0; kb < 8; ++kb) {
        __syncthreads();
        #pragma unroll
        for (int p = 0; p < 4; p++) {
            int ch = wave + p * 4;
            int r  = ch * 8 + srow;
            gl_lds16(&Xin[(mbase + r) * 512 + kb * 64 + scol * 8],
                     &As[ch * 8 * 64]);
            gl_lds16(&Wob[(nbase + r) * 512 + kb * 64 + scol * 8],
                     &Bs[ch * 8 * 64]);
        }
        __syncthreads();
        #pragma unroll
        for (int k0i = 0; k0i < 2; k0i++) {
            s16x8 af[4], bf[4];
            #pragma unroll
            for (int mi = 0; mi < 4; mi++)
                af[mi] = *(const s16x8*)&As[(waveM + mi * 16 + l16) * 64
                                            + (((k0i * 4 + quad) ^ cxa) * 8)];
            #pragma unroll
            for (int ni = 0; ni < 4; ni++)
                bf[ni] = *(const s16x8*)&Bs[(waveN + ni * 16 + l16) * 64
                                            + (((k0i * 4 + quad) ^ cxa) * 8)];
            #pragma unroll
            for (int mi = 0; mi < 4; mi++)
                #pragma unroll
                for (int ni = 0; ni < 4; ni++)
                    acc[mi][ni] = __builtin_amdgcn_mfma_f32_16x16x32_bf16(
                        af[mi], bf[ni], acc[mi][ni], 0, 0, 0);
        }
    }

    #pragma unroll
    for (int mi = 0; mi < 4; mi++) {
        #pragma unroll
        for (int ni = 0; ni < 4; ni++) {
            #pragma unroll
            for (int r = 0; r < 4; r++) {
                int t = mbase + waveM + mi * 16 + quad * 4 + r;
                int o = nbase + waveN + ni * 16 + l16;
                out[t * 512 + o] = acc[mi][ni][r] + bo[o];
            }
        }
    }
}

// ---------------------------------------------------------------------------
// Kernel 3 (legacy, f32-staged Wo) — small-workspace fallback.
// ---------------------------------------------------------------------------
__global__ __launch_bounds__(256) void out_gemm(
    const short* __restrict__ Xin,
    const float* __restrict__ Wo, const float* __restrict__ bo,
    float* __restrict__ out)
{
    __shared__ short As[128 * LDT];
    __shared__ short Bs[128 * LDT];

    const int tid  = threadIdx.x;
    const int wave = tid >> 6, lane = tid & 63;
    const int quad = lane >> 4, l16 = lane & 15;
    const int waveM = (wave >> 1) * 64, waveN = (wave & 1) * 64;
    const int mbase = blockIdx.y * 128;
    const int nbase = blockIdx.x * 128;

    f32x4 acc[4][4];
    #pragma unroll
    for (int i = 0; i < 4; i++)
        #pragma unroll
        for (int j = 0; j < 4; j++)
            acc[i][j] = (f32x4){0.f, 0.f, 0.f, 0.f};

    for (int kb = 0; kb < 8; ++kb) {
        __syncthreads();
        #pragma unroll
        for (int p = 0; p < 4; p++) {
            int chunk = tid + p * 256;
            int row = chunk >> 3, c = chunk & 7;
            *(s16x8*)&As[row * LDT + c * 8] =
                *(const s16x8*)&Xin[(mbase + row) * 512 + kb * 64 + c * 8];
        }
        #pragma unroll
        for (int p = 0; p < 8; p++) {
            int chunk = tid + p * 256;
            int row = chunk >> 4, c = chunk & 15;
            float4 w4 = *(const float4*)&Wo[(nbase + row) * 512 + kb * 64 + c * 4];
            *(uint2*)&Bs[row * LDT + c * 4] = cvt4(w4);
        }
        __syncthreads();
        #pragma unroll
        for (int k0i = 0; k0i < 2; k0i++) {
            s16x8 af[4], bf[4];
            #pragma unroll
            for (int mi = 0; mi < 4; mi++)
                af[mi] = *(const s16x8*)&As[(waveM + mi * 16 + l16) * LDT + (k0i * 4 + quad) * 8];
            #pragma unroll
            for (int ni = 0; ni < 4; ni++)
                bf[ni] = *(const s16x8*)&Bs[(waveN + ni * 16 + l16) * LDT + (k0i * 4 + quad) * 8];
            #pragma unroll
            for (int mi = 0; mi < 4; mi++)
                #pragma unroll
                for (int ni = 0; ni < 4; ni++)
                    acc[mi][ni] = __builtin_amdgcn_mfma_f32_16x16x32_bf16(
                        af[mi], bf[ni], acc[mi][ni], 0, 0, 0);
        }
    }

    #pragma unroll
    for (int mi = 0; mi < 4; mi++) {
        #pragma unroll
        for (int ni = 0; ni < 4; ni++) {
            #pragma unroll
            for (int r = 0; r < 4; r++) {
                int t = mbase + waveM + mi * 16 + quad * 4 + r;
                int o = nbase + waveN + ni * 16 + l16;
                out[t * 512 + o] = acc[mi][ni][r] + bo[o];
            }
        }
    }
}

// ---------------------------------------------------------------------------
extern "C" void kernel_launch(void* const* d_in, const int* in_sizes, int n_in,
                              void* d_out, int out_size, void* d_ws, size_t ws_size,
                              hipStream_t stream) {
    const float* src  = (const float*)d_in[0];
    const float* bias = (const float*)d_in[1];
    const float* Wq   = (const float*)d_in[2];
    const float* bq   = (const float*)d_in[3];
    const float* Wk   = (const float*)d_in[4];
    const float* bk   = (const float*)d_in[5];
    const float* Wv   = (const float*)d_in[6];
    const float* bv   = (const float*)d_in[7];
    const float* Wo   = (const float*)d_in[8];
    const float* bo   = (const float*)d_in[9];

    short* ws = (short*)d_ws;
    short* Qb = ws;                        // [B][NH][A][HD] bf16, 16 MB (Q pre-scaled)
    short* Kb = ws + (size_t)(1 << 23);    // 16 MB
    short* Vb = ws + (size_t)(2 << 23);    // 16 MB

    const bool big2   = ws_size >= (size_t)(66u << 20);   // +Sb/Wall layout
    const bool big_ws = ws_size >= (size_t)(64u << 20);

    if (big2) {
        short* Sb   = ws + (size_t)3 * (1 << 23);   // src bf16, 16 MB (dies after qkv)
        short* Wall = ws + (size_t)4 * (1 << 23);   // Wq|Wk|Wv|Wo bf16, 2 MB
        short* AO   = Sb;                           // attn output overlays dead Sb
        short* Vtb  = (short*)d_out;                // V^T scratch; out_gemm overwrites

        cvt_all<<<dim3(4608), 256, 0, stream>>>(src, Sb, Wq, Wk, Wv, Wo, Wall);
        qkv_gemm_bf<<<dim3(12, 128), 256, 0, stream>>>(Sb, Wall, bq, bk, bv, Qb, Kb, Vb);
        v_tr<<<dim3(16, 128), 256, 0, stream>>>(Vb, Vtb);
        attn_kernel2<<<dim3(16, 128), 256, 0, stream>>>(Qb, Kb, Vtb, bias, AO);
        out_gemm_bf<<<dim3(4, 128), 256, 0, stream>>>(AO, Wall + 3 * (DM * DM), bo,
                                                      (float*)d_out);
    } else {
        short* AO = big_ws ? (ws + (size_t)3 * (1 << 23))
                           : (short*)d_out;

        qkv_gemm<<<dim3(12, 128), 256, 0, stream>>>(src, Wq, bq, Wk, bk, Wv, bv, Qb, Kb, Vb);
        attn_kernel<<<dim3(16, 128), 256, 0, stream>>>(Qb, Kb, Vb, bias, AO);

        if (big_ws) {
            out_gemm<<<dim3(4, 128), 256, 0, stream>>>(AO, Wo, bo, (float*)d_out);
        } else {
            float* Cs = (float*)d_ws;
            out_gemm<<<dim3(4, 128), 256, 0, stream>>>(AO, Wo, bo, Cs);
            (void)hipMemcpyAsync(d_out, Cs, (size_t)out_size * sizeof(float),
                                 hipMemcpyDeviceToDevice, stream);
        }
    }
}